// Round 14
// baseline (98.352 us; speedup 1.0000x reference)
//
#include <hip/hip_runtime.h>
#include <math.h>

// z:     [16, 64, 32, 32] f32 -> N = 16384 queries of dim 64
// emb_w: [16384, 64] f32
// out:   1048576 f32 (z_q bchw) + 1 f32 (loss)
#define NQ      16384
#define NE      16384
#define DIM     64
#define QB      256               // queries per block/wave (8 qg in 128 VGPR)
#define CS1     8                 // 64 x 8 = 512 blocks
#define CPB1    (NE / CS1)        // 2048 codes per block
#define CPW1    (CPB1 / 4)        // 512 codes per wave
#define NT1     (CPW1 / 32)       // 16 tiles of 32 codes
#define THREADS 256
#define EPS     0.4f              // 2.5x the fp16-single score error bound (<=0.16)

typedef _Float16 half8  __attribute__((ext_vector_type(8)));
typedef float    f32x4  __attribute__((ext_vector_type(4)));
typedef float    f32x16 __attribute__((ext_vector_type(16)));
typedef unsigned int       uint32;
typedef unsigned short     uint16;
typedef unsigned long long uint64;

typedef union { f32x16 v; f32x4 q[4]; } nvec16;

// ---------------- ws layout (f32 words), total ~10.0 MB ----------------
#define W_NORMS   0
#define W_PM1     16384      // float[8*16384]
#define W_PM2     147456     // float[8*16384]
#define W_PG      278528     // uint16[8*16384] = 65536 words
#define W_FINALG  344064     // uint32[16384]
#define W_RLIST   360448     // uint32[16384]
#define W_COUNT   376832
#define W_LOSSP   376848     // float[256]
#define W_RKEY    377104     // uint64[16384], 8B aligned
#define W_ZH1     409872
#define W_ZH2     934160
#define W_EH1     1458448
#define W_EH2     1982736

__device__ inline uint32 fmono(float f) {   // monotone float->u32 (min-order preserved)
    uint32 u = __float_as_uint(f);
    return (u & 0x80000000u) ? ~u : (u | 0x80000000u);
}

// Fused prep, 4 threads per row (R13's 128-block version was 0.5 block/CU,
// latency-bound). Blocks [0,256): -2*emb split to fp16 hi/lo + ||e||^2 via
// 4-lane shfl reduce. Blocks [256,512): z gather/split. Also zeroes count.
__global__ __launch_bounds__(THREADS)
void vq_prep(const float* __restrict__ z, const float* __restrict__ emb,
             _Float16* __restrict__ zh1, _Float16* __restrict__ zh2,
             _Float16* __restrict__ eh1, _Float16* __restrict__ eh2,
             float* __restrict__ norms, uint32* __restrict__ count) {
    if (blockIdx.x == 0 && threadIdx.x == 0) *count = 0u;   // reset per call
    if (blockIdx.x < 256) {
        int gid = blockIdx.x * THREADS + threadIdx.x;   // 0..65535
        int e = gid >> 2, p = gid & 3;                  // row, quarter
        const float4* row = reinterpret_cast<const float4*>(emb + (size_t)e * DIM + p * 16);
        float s = 0.f;
#pragma unroll
        for (int i = 0; i < 4; ++i) {
            float4 v = row[i];
            s = fmaf(v.x, v.x, s); s = fmaf(v.y, v.y, s);
            s = fmaf(v.z, v.z, s); s = fmaf(v.w, v.w, s);
            union { _Float16 h[4]; uint2 u; } p1, p2;
            float f[4] = {-2.f * v.x, -2.f * v.y, -2.f * v.z, -2.f * v.w};
#pragma unroll
            for (int j = 0; j < 4; ++j) {
                _Float16 h1 = (_Float16)f[j];
                p1.h[j] = h1;
                p2.h[j] = (_Float16)(f[j] - (float)h1);
            }
            *reinterpret_cast<uint2*>(eh1 + (size_t)e * DIM + p * 16 + i * 4) = p1.u;
            *reinterpret_cast<uint2*>(eh2 + (size_t)e * DIM + p * 16 + i * 4) = p2.u;
        }
        s += __shfl_xor(s, 1, 64);
        s += __shfl_xor(s, 2, 64);
        if (p == 0) norms[e] = s;
    } else {
        int gid = (blockIdx.x - 256) * THREADS + threadIdx.x;
        int n = gid >> 2, p = gid & 3;
        const float* zp = z + (size_t)(n >> 10) * 65536 + (n & 1023) + (size_t)(p * 16) * 1024;
#pragma unroll
        for (int i4 = 0; i4 < 4; ++i4) {
            union { _Float16 h[4]; uint2 u; } p1, p2;
#pragma unroll
            for (int j = 0; j < 4; ++j) {
                float x = zp[(size_t)(i4 * 4 + j) * 1024];
                _Float16 h1 = (_Float16)x;
                p1.h[j] = h1;
                p2.h[j] = (_Float16)(x - (float)h1);
            }
            *reinterpret_cast<uint2*>(zh1 + (size_t)n * DIM + p * 16 + i4 * 4) = p1.u;
            *reinterpret_cast<uint2*>(zh2 + (size_t)n * DIM + p * 16 + i4 * 4) = p2.u;
        }
    }
}

// PASS 1: 32x32x16 MFMA, codes-as-A, 256 q/wave, norms on scalar pipe (R12),
// A-reuse 32 MFMAs/load (R13). NEW (R14): 1-qg-deep accumulator pipeline —
// issue qg+1's MFMA chain into the alternate acc BEFORE qg's min-tree, so the
// min VALU executes under the next chain's matrix latency (R13 PMC: MFMA+TA+
// VALU summed to ~97% of wall = fully serialized in-order issue).
#define LOADT(AS, TL) {                                                            \
    const _Float16* _pa = eh1 + (size_t)(cwbase + (TL) * 32 + q31) * DIM + hi8;    \
    AS[0] = *reinterpret_cast<const half8*>(_pa);                                  \
    AS[1] = *reinterpret_cast<const half8*>(_pa + 16);                             \
    AS[2] = *reinterpret_cast<const half8*>(_pa + 32);                             \
    AS[3] = *reinterpret_cast<const half8*>(_pa + 48); }

#define LOADSN(SN, TL) {                                                           \
    _Pragma("unroll")                                                              \
    for (int k = 0; k < 32; ++k) SN[k] = nrm_s[(TL) * 32 + k]; }

#define MKNS(NS, SN) {                                                             \
    _Pragma("unroll")                                                              \
    for (int j = 0; j < 16; ++j)                                                   \
        NS.v[j] = hi ? SN[(j >> 2) * 8 + 4 + (j & 3)] : SN[(j >> 2) * 8 + (j & 3)]; }

#define CHAIN(ACC, AS, NS, QG)                                                     \
    __builtin_amdgcn_s_setprio(1);                                                 \
    ACC = __builtin_amdgcn_mfma_f32_32x32x16_f16(AS[0], B[QG][0], NS.v, 0, 0, 0);  \
    ACC = __builtin_amdgcn_mfma_f32_32x32x16_f16(AS[1], B[QG][1], ACC,  0, 0, 0);  \
    ACC = __builtin_amdgcn_mfma_f32_32x32x16_f16(AS[2], B[QG][2], ACC,  0, 0, 0);  \
    ACC = __builtin_amdgcn_mfma_f32_32x32x16_f16(AS[3], B[QG][3], ACC,  0, 0, 0);  \
    __builtin_amdgcn_s_setprio(0);

#define MINTRK(ACC, QG, TID) {                                                     \
    float u0 = fminf(fminf(ACC[0],  ACC[1]),  ACC[2]);                             \
    float u1 = fminf(fminf(ACC[3],  ACC[4]),  ACC[5]);                             \
    float u2 = fminf(fminf(ACC[6],  ACC[7]),  ACC[8]);                             \
    float u3 = fminf(fminf(ACC[9],  ACC[10]), ACC[11]);                            \
    float u4 = fminf(fminf(ACC[12], ACC[13]), ACC[14]);                            \
    float v  = fminf(fminf(fminf(u0, u1), u2), fminf(fminf(u3, u4), ACC[15]));     \
    float nm2 = fminf(m2[QG], fmaxf(v, mv[QG]));    /* uses OLD mv */              \
    bool lt = v < mv[QG];                           /* first-min: strict < */      \
    mv[QG] = lt ? v : mv[QG];                                                      \
    mi[QG] = lt ? (TID) : mi[QG];                                                  \
    m2[QG] = nm2; }

#define COMPUTE(AS, NS, TL) {                                                      \
    const uint32 _tid = (uint32)(TL);                                              \
    f32x16 aA, aB;                                                                 \
    CHAIN(aA, AS, NS, 0)                                                           \
    CHAIN(aB, AS, NS, 1) MINTRK(aA, 0, _tid)                                       \
    CHAIN(aA, AS, NS, 2) MINTRK(aB, 1, _tid)                                       \
    CHAIN(aB, AS, NS, 3) MINTRK(aA, 2, _tid)                                       \
    CHAIN(aA, AS, NS, 4) MINTRK(aB, 3, _tid)                                       \
    CHAIN(aB, AS, NS, 5) MINTRK(aA, 4, _tid)                                       \
    CHAIN(aA, AS, NS, 6) MINTRK(aB, 5, _tid)                                       \
    CHAIN(aB, AS, NS, 7) MINTRK(aA, 6, _tid)                                       \
    MINTRK(aB, 7, _tid) }

__global__ __launch_bounds__(THREADS, 2)
void vq_pass1(const _Float16* __restrict__ zh1, const _Float16* __restrict__ eh1,
              const float* __restrict__ norms,
              float* __restrict__ pm1, float* __restrict__ pm2, uint16* __restrict__ pg) {
    __shared__ float  redv[4][QB];
    __shared__ float  red2[4][QB];
    __shared__ uint32 redg[4][QB];

    const int t    = threadIdx.x;
    const int lane = t & 63;
    const int wave = t >> 6;
    const int q31  = lane & 31;
    const int hi   = lane >> 5;
    const int hi8  = hi * 8;
    const int qbase  = blockIdx.x * QB;
    const int cwbase = blockIdx.y * CPB1 + wave * CPW1;

    // uniform (SGPR) norm base for this wave -> scalar loads
    const float* nrm_s = norms + (size_t)__builtin_amdgcn_readfirstlane(cwbase);

    // B fragments (queries): col = q31, k = kc*16 + hi*8
    half8 B[8][4];
#pragma unroll
    for (int qg = 0; qg < 8; ++qg)
#pragma unroll
        for (int kc = 0; kc < 4; ++kc)
            B[qg][kc] = *reinterpret_cast<const half8*>(
                zh1 + (size_t)(qbase + qg * 32 + q31) * DIM + kc * 16 + hi8);

    float  mv[8], m2[8];
    uint32 mi[8];
#pragma unroll
    for (int q = 0; q < 8; ++q) { mv[q] = INFINITY; m2[q] = INFINITY; mi[q] = 0u; }

    half8 A0[4], A1[4];
    float sn0[32], sn1[32];

    LOADT(A0, 0) LOADSN(sn0, 0)
    for (int tb = 0; tb < NT1; tb += 2) {
        LOADT(A1, tb + 1) LOADSN(sn1, tb + 1)
        {
            nvec16 N0; MKNS(N0, sn0)
            COMPUTE(A0, N0, tb)
        }
        int nx = (tb + 2 < NT1) ? tb + 2 : 0;   // clamped tail (unused)
        LOADT(A0, nx) LOADSN(sn0, nx)
        {
            nvec16 N1; MKNS(N1, sn1)
            COMPUTE(A1, N1, tb + 1)
        }
    }

    // gid = global 16-code group = (abs 32-tile)*2 + hi
    uint32 gi[8];
#pragma unroll
    for (int qg = 0; qg < 8; ++qg)
        gi[qg] = ((uint32)(cwbase >> 5) + mi[qg]) * 2u + (uint32)hi;

    // merge the two hi halves (same query, disjoint groups)
#pragma unroll
    for (int qg = 0; qg < 8; ++qg) {
        float  ov = __shfl_xor(mv[qg], 32, 64);
        float  o2 = __shfl_xor(m2[qg], 32, 64);
        uint32 og = (uint32)__shfl_xor((int)gi[qg], 32, 64);
        float nm2 = fminf(fminf(m2[qg], o2), fmaxf(mv[qg], ov));
        if (ov < mv[qg] || (ov == mv[qg] && og < gi[qg])) { mv[qg] = ov; gi[qg] = og; }
        m2[qg] = nm2;
    }
    if (lane < 32) {
#pragma unroll
        for (int qg = 0; qg < 8; ++qg) {
            redv[wave][qg * 32 + lane] = mv[qg];
            red2[wave][qg * 32 + lane] = m2[qg];
            redg[wave][qg * 32 + lane] = gi[qg];
        }
    }
    __syncthreads();

    // cross-wave reduce (ascending wave = ascending code range, strict <)
    {
        float  bv = redv[0][t], b2 = red2[0][t];
        uint32 bg = redg[0][t];
#pragma unroll
        for (int w = 1; w < 4; ++w) {
            float v = redv[w][t], s2 = red2[w][t];
            float nm2 = fminf(fminf(b2, s2), fmaxf(bv, v));
            if (v < bv) { bv = v; bg = redg[w][t]; }
            b2 = nm2;
        }
        pm1[(size_t)blockIdx.y * NQ + qbase + t] = bv;
        pm2[(size_t)blockIdx.y * NQ + qbase + t] = b2;
        pg [(size_t)blockIdx.y * NQ + qbase + t] = (uint16)bg;
    }
}

// SELECT: merge the 8 splits' (m1,g,m2); margin test; compact failures.
__global__ __launch_bounds__(THREADS)
void vq_select(const float* __restrict__ pm1, const float* __restrict__ pm2,
               const uint16* __restrict__ pg,
               uint32* __restrict__ final_g, uint32* __restrict__ rlist,
               uint32* __restrict__ count, uint64* __restrict__ rkey) {
    const int n = blockIdx.x * THREADS + threadIdx.x;
    float M1 = INFINITY, M2 = INFINITY;
    uint32 G = 0u;
#pragma unroll
    for (int s = 0; s < CS1; ++s) {
        float  m1  = pm1[(size_t)s * NQ + n];
        float  m2s = pm2[(size_t)s * NQ + n];
        uint32 g   = (uint32)pg[(size_t)s * NQ + n];
        float nm2 = fminf(fminf(M2, m2s), fmaxf(M1, m1));
        if (m1 < M1) { M1 = m1; G = g; }    // ascending split -> first-min
        M2 = nm2;
    }
    rkey[n] = ~0ull;                        // init for rescue atomicMin
    if (M2 - M1 > EPS) {
        final_g[n] = G;                     // provably contains the true argmin
    } else {
        final_g[n] = 0xFFFFFFFFu;           // sentinel -> rescue
        uint32 p = atomicAdd(count, 1u);
        rlist[p] = (uint32)n;
    }
}

// RESCUE: exact-grade fp16x2 (6-MFMA, 16x16) full-codebook argmin for flagged
// queries; (score, 4-code-gid) merged via atomicMin on monotone u64 key.
__global__ __launch_bounds__(THREADS, 2)
void vq_rescue(const _Float16* __restrict__ zh1, const _Float16* __restrict__ zh2,
               const _Float16* __restrict__ eh1, const _Float16* __restrict__ eh2,
               const float* __restrict__ norms,
               const uint32* __restrict__ rlist, const uint32* __restrict__ countp,
               uint64* __restrict__ rkey) {
    __shared__ float  redv[4][128];
    __shared__ uint32 redg[4][128];

    const uint32 count = *countp;
    const uint32 nch   = (count + 127u) >> 7;
    const int t    = threadIdx.x;
    const int lane = t & 63;
    const int wave = t >> 6;
    const int r15  = lane & 15, hk = lane >> 4;
    const int cy   = blockIdx.x & 15;
    const int rcb  = cy * 1024 + wave * 256;   // this wave's code range (16 tiles)

    for (uint32 cx = (uint32)(blockIdx.x >> 4); cx < nch; cx += 32u) {
        half8 B1[8][2], B2[8][2];
#pragma unroll
        for (int qt = 0; qt < 8; ++qt) {
            uint32 j = cx * 128u + (uint32)(qt * 16 + r15);
            uint32 qid = (j < count) ? rlist[j] : 0u;
#pragma unroll
            for (int kc = 0; kc < 2; ++kc) {
                size_t off = (size_t)qid * DIM + kc * 32 + hk * 8;
                B1[qt][kc] = *reinterpret_cast<const half8*>(zh1 + off);
                B2[qt][kc] = *reinterpret_cast<const half8*>(zh2 + off);
            }
        }

        float  mv[8];
        uint32 mi[8];
#pragma unroll
        for (int q = 0; q < 8; ++q) { mv[q] = INFINITY; mi[q] = 0u; }

        half8 a1[2], a2[2];
        f32x4 nc;
        {
            const _Float16* p1 = eh1 + (size_t)(rcb + r15) * DIM + hk * 8;
            const _Float16* p2 = eh2 + (size_t)(rcb + r15) * DIM + hk * 8;
            a1[0] = *reinterpret_cast<const half8*>(p1);
            a1[1] = *reinterpret_cast<const half8*>(p1 + 32);
            a2[0] = *reinterpret_cast<const half8*>(p2);
            a2[1] = *reinterpret_cast<const half8*>(p2 + 32);
            nc = *reinterpret_cast<const f32x4*>(norms + rcb + hk * 4);
        }

#pragma unroll 2
        for (int tile = 0; tile < 16; ++tile) {
            int nt = (tile + 1 < 16) ? tile + 1 : tile;
            half8 b1[2], b2[2];
            f32x4 nn;
            {
                const _Float16* p1 = eh1 + (size_t)(rcb + nt * 16 + r15) * DIM + hk * 8;
                const _Float16* p2 = eh2 + (size_t)(rcb + nt * 16 + r15) * DIM + hk * 8;
                b1[0] = *reinterpret_cast<const half8*>(p1);
                b1[1] = *reinterpret_cast<const half8*>(p1 + 32);
                b2[0] = *reinterpret_cast<const half8*>(p2);
                b2[1] = *reinterpret_cast<const half8*>(p2 + 32);
                nn = *reinterpret_cast<const f32x4*>(norms + rcb + nt * 16 + hk * 4);
            }

            f32x4 acc[8];
            __builtin_amdgcn_s_setprio(1);
#pragma unroll
            for (int qt = 0; qt < 8; ++qt) {
                acc[qt] = __builtin_amdgcn_mfma_f32_16x16x32_f16(a1[0], B1[qt][0], nc,      0, 0, 0);
                acc[qt] = __builtin_amdgcn_mfma_f32_16x16x32_f16(a1[1], B1[qt][1], acc[qt], 0, 0, 0);
                acc[qt] = __builtin_amdgcn_mfma_f32_16x16x32_f16(a1[0], B2[qt][0], acc[qt], 0, 0, 0);
                acc[qt] = __builtin_amdgcn_mfma_f32_16x16x32_f16(a1[1], B2[qt][1], acc[qt], 0, 0, 0);
                acc[qt] = __builtin_amdgcn_mfma_f32_16x16x32_f16(a2[0], B1[qt][0], acc[qt], 0, 0, 0);
                acc[qt] = __builtin_amdgcn_mfma_f32_16x16x32_f16(a2[1], B1[qt][1], acc[qt], 0, 0, 0);
            }
            __builtin_amdgcn_s_setprio(0);

            const uint32 tid = (uint32)tile;
#pragma unroll
            for (int qt = 0; qt < 8; ++qt) {
                float v = fminf(fminf(fminf(acc[qt][0], acc[qt][1]), acc[qt][2]), acc[qt][3]);
                bool lt = v < mv[qt];
                mv[qt] = lt ? v : mv[qt];
                mi[qt] = lt ? tid : mi[qt];
            }
            a1[0] = b1[0]; a1[1] = b1[1];
            a2[0] = b2[0]; a2[1] = b2[1];
            nc = nn;
        }

        uint32 gi[8];
#pragma unroll
        for (int q = 0; q < 8; ++q)
            gi[q] = (uint32)(rcb >> 2) + (mi[q] << 2) + (uint32)hk;
#pragma unroll
        for (int st = 16; st < 64; st <<= 1) {
#pragma unroll
            for (int q = 0; q < 8; ++q) {
                float  ov = __shfl_xor(mv[q], st, 64);
                uint32 og = (uint32)__shfl_xor((int)gi[q], st, 64);
                if (ov < mv[q] || (ov == mv[q] && og < gi[q])) { mv[q] = ov; gi[q] = og; }
            }
        }
        if (lane < 16) {
#pragma unroll
            for (int qt = 0; qt < 8; ++qt) {
                redv[wave][qt * 16 + lane] = mv[qt];
                redg[wave][qt * 16 + lane] = gi[qt];
            }
        }
        __syncthreads();
        if (t < 128) {
            float  bv = redv[0][t];
            uint32 bg = redg[0][t];
#pragma unroll
            for (int w = 1; w < 4; ++w) {   // ascending wave = ascending codes
                float v = redv[w][t];
                if (v < bv) { bv = v; bg = redg[w][t]; }
            }
            uint32 j = cx * 128u + (uint32)t;
            if (j < count) {
                uint64 key = ((uint64)fmono(bv) << 32) | (uint64)bg;
                atomicMin(rkey + rlist[j], key);
            }
        }
        __syncthreads();   // LDS reuse across cx iterations
    }
}

// FINALIZE: unified 16-candidate path. Margin queries: group = pass1 16-gid.
// Rescued queries: the 4-code quad lies inside one (tile,hi) 16-group ->
// superset decode. 4 lanes/query; exact fp32 re-eval, ascending code = first-min.
__global__ __launch_bounds__(THREADS)
void vq_finalize(const float* __restrict__ z,
                 const float* __restrict__ emb,
                 const float* __restrict__ norms,
                 const uint32* __restrict__ final_g,
                 const uint64* __restrict__ rkey,
                 float* __restrict__ out,
                 float* __restrict__ lossp) {
    const int t  = threadIdx.x;
    const int ql = t >> 2, p = t & 3;
    const int n  = blockIdx.x * 64 + ql;
    const int c0 = p * 16;

    uint32 bg = final_g[n];
    if (bg == 0xFFFFFFFFu) {
        uint32 c4 = (uint32)(rkey[n] & 0xFFFFFFFFull) * 4u;   // first code of quad
        bg = (c4 >> 5) * 2u + ((c4 >> 2) & 1u);
    }
    const int gbase = (int)((bg >> 1) * 32u + (bg & 1u) * 4u);

    const float* zp = z + (size_t)(n >> 10) * 65536 + (n & 1023);
    float zq[16];
#pragma unroll
    for (int c = 0; c < 16; ++c) zq[c] = zp[(size_t)(c0 + c) * 1024];

    // partial dots over this lane's 16 channels, 16 candidates
    float dp[16];
#pragma unroll
    for (int j = 0; j < 16; ++j) {
        int code = gbase + (j & 3) + 8 * (j >> 2);
        const float4* er = reinterpret_cast<const float4*>(emb + (size_t)code * DIM + c0);
        float d = 0.f;
#pragma unroll
        for (int i = 0; i < 4; ++i) {
            float4 e4 = er[i];
            d = fmaf(e4.x, zq[i * 4 + 0], d);
            d = fmaf(e4.y, zq[i * 4 + 1], d);
            d = fmaf(e4.z, zq[i * 4 + 2], d);
            d = fmaf(e4.w, zq[i * 4 + 3], d);
        }
        dp[j] = d;
    }
#pragma unroll
    for (int st = 1; st < 4; st <<= 1) {
#pragma unroll
        for (int j = 0; j < 16; ++j) dp[j] += __shfl_xor(dp[j], st, 64);
    }

    f32x4 nr[4];
#pragma unroll
    for (int k = 0; k < 4; ++k)
        nr[k] = *reinterpret_cast<const f32x4*>(norms + gbase + k * 8);

    float bs = INFINITY;
    uint32 bi = 0u;
#pragma unroll
    for (int j = 0; j < 16; ++j) {   // ascending code order within group
        float s = fmaf(-2.f, dp[j], nr[j >> 2][j & 3]);
        uint32 code = (uint32)(gbase + (j & 3) + 8 * (j >> 2));
        if (s < bs) { bs = s; bi = code; }   // strict < -> first-min
    }

    const float* ew = emb + (size_t)bi * DIM + c0;
    float* op = out + (size_t)(n >> 10) * 65536 + (n & 1023);

    float ls = 0.f;
#pragma unroll
    for (int c = 0; c < 16; ++c) {
        float e = ew[c];
        op[(size_t)(c0 + c) * 1024] = e;
        float d = e - zq[c];
        ls = fmaf(d, d, ls);
    }

#pragma unroll
    for (int off = 32; off > 0; off >>= 1) ls += __shfl_down(ls, off, 64);
    __shared__ float wsum[THREADS / 64];
    if ((t & 63) == 0) wsum[t >> 6] = ls;
    __syncthreads();
    if (t == 0) {
        float s = 0.f;
#pragma unroll
        for (int w = 0; w < THREADS / 64; ++w) s += wsum[w];
        lossp[blockIdx.x] = s;
    }
}

__global__ __launch_bounds__(64)
void vq_loss_final(const float* __restrict__ lossp, float* __restrict__ out) {
    float v = 0.f;
#pragma unroll
    for (int k = 0; k < 4; ++k) v += lossp[threadIdx.x + k * 64];
#pragma unroll
    for (int off = 32; off > 0; off >>= 1) v += __shfl_down(v, off, 64);
    if (threadIdx.x == 0)
        out[1048576] = 0.25f * v / 1048576.0f;   // BETA * mean
}

extern "C" void kernel_launch(void* const* d_in, const int* in_sizes, int n_in,
                              void* d_out, int out_size, void* d_ws, size_t ws_size,
                              hipStream_t stream) {
    const float* z   = (const float*)d_in[0];
    const float* emb = (const float*)d_in[1];
    float* out = (float*)d_out;

    float* ws = (float*)d_ws;
    float*     norms   = ws + W_NORMS;
    float*     pm1     = ws + W_PM1;
    float*     pm2     = ws + W_PM2;
    uint16*    pg      = (uint16*)(ws + W_PG);
    uint32*    final_g = (uint32*)(ws + W_FINALG);
    uint32*    rlist   = (uint32*)(ws + W_RLIST);
    uint32*    count   = (uint32*)(ws + W_COUNT);
    float*     lossp   = ws + W_LOSSP;
    uint64*    rkey    = (uint64*)(ws + W_RKEY);
    _Float16*  zh1     = (_Float16*)(ws + W_ZH1);
    _Float16*  zh2     = (_Float16*)(ws + W_ZH2);
    _Float16*  eh1     = (_Float16*)(ws + W_EH1);
    _Float16*  eh2     = (_Float16*)(ws + W_EH2);

    vq_prep<<<512, THREADS, 0, stream>>>(z, emb, zh1, zh2, eh1, eh2, norms, count);

    dim3 g1(NQ / QB, CS1);   // 64 x 8 = 512 blocks
    vq_pass1<<<g1, THREADS, 0, stream>>>(zh1, eh1, norms, pm1, pm2, pg);

    vq_select<<<NQ / THREADS, THREADS, 0, stream>>>(pm1, pm2, pg, final_g, rlist, count, rkey);

    vq_rescue<<<512, THREADS, 0, stream>>>(zh1, zh2, eh1, eh2, norms, rlist, count, rkey);

    vq_finalize<<<NQ / 64, THREADS, 0, stream>>>(z, emb, norms, final_g, rkey, out, lossp);
    vq_loss_final<<<1, 64, 0, stream>>>(lossp, out);
}

// Round 15
// 78.629 us; speedup vs baseline: 1.2508x; 1.2508x over previous
//
#include <hip/hip_runtime.h>
#include <math.h>

// z:     [16, 64, 32, 32] f32 -> N = 16384 queries of dim 64
// emb_w: [16384, 64] f32
// out:   1048576 f32 (z_q bchw) + 1 f32 (loss)
#define NQ      16384
#define NE      16384
#define DIM     64
#define QB      256               // queries per block/wave (8 qg in 128 VGPR)
#define CS1     8                 // 64 x 8 = 512 blocks
#define CPB1    (NE / CS1)        // 2048 codes per block
#define CPW1    (CPB1 / 4)        // 512 codes per wave
#define NT1     (CPW1 / 32)       // 16 tiles of 32 codes
#define THREADS 256
#define EPS     0.4f              // 2.5x the fp16-single score error bound (<=0.16)

typedef _Float16 half8  __attribute__((ext_vector_type(8)));
typedef float    f32x4  __attribute__((ext_vector_type(4)));
typedef float    f32x16 __attribute__((ext_vector_type(16)));
typedef unsigned int       uint32;
typedef unsigned short     uint16;
typedef unsigned long long uint64;

typedef union { f32x16 v; f32x4 q[4]; } nvec16;

// ---------------- ws layout (f32 words), total ~10.0 MB ----------------
#define W_NORMS   0
#define W_PM1     16384      // float[8*16384]
#define W_PM2     147456     // float[8*16384]
#define W_PG      278528     // uint16[8*16384] = 65536 words
#define W_FINALG  344064     // uint32[16384]
#define W_RLIST   360448     // uint32[16384]
#define W_COUNT   376832
#define W_LOSSP   376848     // float[256]
#define W_RKEY    377104     // uint64[16384], 8B aligned
#define W_ZH1     409872
#define W_ZH2     934160
#define W_EH1     1458448
#define W_EH2     1982736

__device__ inline uint32 fmono(float f) {   // monotone float->u32 (min-order preserved)
    uint32 u = __float_as_uint(f);
    return (u & 0x80000000u) ? ~u : (u | 0x80000000u);
}

// Fused prep, 4 threads per row (R14 win: +10 us vs 128-block version).
// Blocks [0,256): -2*emb split to fp16 hi/lo + ||e||^2 via 4-lane shfl reduce.
// Blocks [256,512): z gather/split. Also zeroes count.
__global__ __launch_bounds__(THREADS)
void vq_prep(const float* __restrict__ z, const float* __restrict__ emb,
             _Float16* __restrict__ zh1, _Float16* __restrict__ zh2,
             _Float16* __restrict__ eh1, _Float16* __restrict__ eh2,
             float* __restrict__ norms, uint32* __restrict__ count) {
    if (blockIdx.x == 0 && threadIdx.x == 0) *count = 0u;   // reset per call
    if (blockIdx.x < 256) {
        int gid = blockIdx.x * THREADS + threadIdx.x;   // 0..65535
        int e = gid >> 2, p = gid & 3;                  // row, quarter
        const float4* row = reinterpret_cast<const float4*>(emb + (size_t)e * DIM + p * 16);
        float s = 0.f;
#pragma unroll
        for (int i = 0; i < 4; ++i) {
            float4 v = row[i];
            s = fmaf(v.x, v.x, s); s = fmaf(v.y, v.y, s);
            s = fmaf(v.z, v.z, s); s = fmaf(v.w, v.w, s);
            union { _Float16 h[4]; uint2 u; } p1, p2;
            float f[4] = {-2.f * v.x, -2.f * v.y, -2.f * v.z, -2.f * v.w};
#pragma unroll
            for (int j = 0; j < 4; ++j) {
                _Float16 h1 = (_Float16)f[j];
                p1.h[j] = h1;
                p2.h[j] = (_Float16)(f[j] - (float)h1);
            }
            *reinterpret_cast<uint2*>(eh1 + (size_t)e * DIM + p * 16 + i * 4) = p1.u;
            *reinterpret_cast<uint2*>(eh2 + (size_t)e * DIM + p * 16 + i * 4) = p2.u;
        }
        s += __shfl_xor(s, 1, 64);
        s += __shfl_xor(s, 2, 64);
        if (p == 0) norms[e] = s;
    } else {
        int gid = (blockIdx.x - 256) * THREADS + threadIdx.x;
        int n = gid >> 2, p = gid & 3;
        const float* zp = z + (size_t)(n >> 10) * 65536 + (n & 1023) + (size_t)(p * 16) * 1024;
#pragma unroll
        for (int i4 = 0; i4 < 4; ++i4) {
            union { _Float16 h[4]; uint2 u; } p1, p2;
#pragma unroll
            for (int j = 0; j < 4; ++j) {
                float x = zp[(size_t)(i4 * 4 + j) * 1024];
                _Float16 h1 = (_Float16)x;
                p1.h[j] = h1;
                p2.h[j] = (_Float16)(x - (float)h1);
            }
            *reinterpret_cast<uint2*>(zh1 + (size_t)n * DIM + p * 16 + i4 * 4) = p1.u;
            *reinterpret_cast<uint2*>(zh2 + (size_t)n * DIM + p * 16 + i4 * 4) = p2.u;
        }
    }
}

// PASS 1: 32x32x16 MFMA, codes-as-A, 256 q/wave, norms on scalar pipe (R12),
// A-reuse 32 MFMAs/load (R13). R13's single-accumulator COMPUTE restored —
// R14's 2-acc pipeline (+16 live VGPR) tripped the allocator into scratch
// spills (FETCH 9.8 -> 45.9 MB, 1.6x slower). Do NOT add live f32x16 state.
#define LOADT(AS, TL) {                                                            \
    const _Float16* _pa = eh1 + (size_t)(cwbase + (TL) * 32 + q31) * DIM + hi8;    \
    AS[0] = *reinterpret_cast<const half8*>(_pa);                                  \
    AS[1] = *reinterpret_cast<const half8*>(_pa + 16);                             \
    AS[2] = *reinterpret_cast<const half8*>(_pa + 32);                             \
    AS[3] = *reinterpret_cast<const half8*>(_pa + 48); }

#define LOADSN(SN, TL) {                                                           \
    _Pragma("unroll")                                                              \
    for (int k = 0; k < 32; ++k) SN[k] = nrm_s[(TL) * 32 + k]; }

#define MKNS(NS, SN) {                                                             \
    _Pragma("unroll")                                                              \
    for (int j = 0; j < 16; ++j)                                                   \
        NS.v[j] = hi ? SN[(j >> 2) * 8 + 4 + (j & 3)] : SN[(j >> 2) * 8 + (j & 3)]; }

#define COMPUTE(AS, NS, TL) {                                                      \
    const uint32 _tid = (uint32)(TL);                                              \
    _Pragma("unroll")                                                              \
    for (int qg = 0; qg < 8; ++qg) {                                               \
        f32x16 acc;                                                                \
        __builtin_amdgcn_s_setprio(1);                                             \
        acc = __builtin_amdgcn_mfma_f32_32x32x16_f16(AS[0], B[qg][0], NS.v, 0, 0, 0); \
        acc = __builtin_amdgcn_mfma_f32_32x32x16_f16(AS[1], B[qg][1], acc,  0, 0, 0); \
        acc = __builtin_amdgcn_mfma_f32_32x32x16_f16(AS[2], B[qg][2], acc,  0, 0, 0); \
        acc = __builtin_amdgcn_mfma_f32_32x32x16_f16(AS[3], B[qg][3], acc,  0, 0, 0); \
        __builtin_amdgcn_s_setprio(0);                                             \
        float u0 = fminf(fminf(acc[0],  acc[1]),  acc[2]);                         \
        float u1 = fminf(fminf(acc[3],  acc[4]),  acc[5]);                         \
        float u2 = fminf(fminf(acc[6],  acc[7]),  acc[8]);                         \
        float u3 = fminf(fminf(acc[9],  acc[10]), acc[11]);                        \
        float u4 = fminf(fminf(acc[12], acc[13]), acc[14]);                        \
        float v  = fminf(fminf(fminf(u0, u1), u2), fminf(fminf(u3, u4), acc[15])); \
        float nm2 = fminf(m2[qg], fmaxf(v, mv[qg]));    /* uses OLD mv */          \
        bool lt = v < mv[qg];                           /* first-min: strict < */  \
        mv[qg] = lt ? v : mv[qg];                                                  \
        mi[qg] = lt ? _tid : mi[qg];                                               \
        m2[qg] = nm2;                                                              \
    } }

__global__ __launch_bounds__(THREADS, 2)
void vq_pass1(const _Float16* __restrict__ zh1, const _Float16* __restrict__ eh1,
              const float* __restrict__ norms,
              float* __restrict__ pm1, float* __restrict__ pm2, uint16* __restrict__ pg) {
    __shared__ float  redv[4][QB];
    __shared__ float  red2[4][QB];
    __shared__ uint32 redg[4][QB];

    const int t    = threadIdx.x;
    const int lane = t & 63;
    const int wave = t >> 6;
    const int q31  = lane & 31;
    const int hi   = lane >> 5;
    const int hi8  = hi * 8;
    const int qbase  = blockIdx.x * QB;
    const int cwbase = blockIdx.y * CPB1 + wave * CPW1;

    // uniform (SGPR) norm base for this wave -> scalar loads
    const float* nrm_s = norms + (size_t)__builtin_amdgcn_readfirstlane(cwbase);

    // B fragments (queries): col = q31, k = kc*16 + hi*8
    half8 B[8][4];
#pragma unroll
    for (int qg = 0; qg < 8; ++qg)
#pragma unroll
        for (int kc = 0; kc < 4; ++kc)
            B[qg][kc] = *reinterpret_cast<const half8*>(
                zh1 + (size_t)(qbase + qg * 32 + q31) * DIM + kc * 16 + hi8);

    float  mv[8], m2[8];
    uint32 mi[8];
#pragma unroll
    for (int q = 0; q < 8; ++q) { mv[q] = INFINITY; m2[q] = INFINITY; mi[q] = 0u; }

    half8 A0[4], A1[4];
    float sn0[32], sn1[32];

    LOADT(A0, 0) LOADSN(sn0, 0)
    for (int tb = 0; tb < NT1; tb += 2) {
        LOADT(A1, tb + 1) LOADSN(sn1, tb + 1)
        {
            nvec16 N0; MKNS(N0, sn0)
            COMPUTE(A0, N0, tb)
        }
        int nx = (tb + 2 < NT1) ? tb + 2 : 0;   // clamped tail (unused)
        LOADT(A0, nx) LOADSN(sn0, nx)
        {
            nvec16 N1; MKNS(N1, sn1)
            COMPUTE(A1, N1, tb + 1)
        }
    }

    // gid = global 16-code group = (abs 32-tile)*2 + hi
    uint32 gi[8];
#pragma unroll
    for (int qg = 0; qg < 8; ++qg)
        gi[qg] = ((uint32)(cwbase >> 5) + mi[qg]) * 2u + (uint32)hi;

    // merge the two hi halves (same query, disjoint groups)
#pragma unroll
    for (int qg = 0; qg < 8; ++qg) {
        float  ov = __shfl_xor(mv[qg], 32, 64);
        float  o2 = __shfl_xor(m2[qg], 32, 64);
        uint32 og = (uint32)__shfl_xor((int)gi[qg], 32, 64);
        float nm2 = fminf(fminf(m2[qg], o2), fmaxf(mv[qg], ov));
        if (ov < mv[qg] || (ov == mv[qg] && og < gi[qg])) { mv[qg] = ov; gi[qg] = og; }
        m2[qg] = nm2;
    }
    if (lane < 32) {
#pragma unroll
        for (int qg = 0; qg < 8; ++qg) {
            redv[wave][qg * 32 + lane] = mv[qg];
            red2[wave][qg * 32 + lane] = m2[qg];
            redg[wave][qg * 32 + lane] = gi[qg];
        }
    }
    __syncthreads();

    // cross-wave reduce (ascending wave = ascending code range, strict <)
    {
        float  bv = redv[0][t], b2 = red2[0][t];
        uint32 bg = redg[0][t];
#pragma unroll
        for (int w = 1; w < 4; ++w) {
            float v = redv[w][t], s2 = red2[w][t];
            float nm2 = fminf(fminf(b2, s2), fmaxf(bv, v));
            if (v < bv) { bv = v; bg = redg[w][t]; }
            b2 = nm2;
        }
        pm1[(size_t)blockIdx.y * NQ + qbase + t] = bv;
        pm2[(size_t)blockIdx.y * NQ + qbase + t] = b2;
        pg [(size_t)blockIdx.y * NQ + qbase + t] = (uint16)bg;
    }
}

// SELECT: merge the 8 splits' (m1,g,m2); margin test; compact failures.
__global__ __launch_bounds__(THREADS)
void vq_select(const float* __restrict__ pm1, const float* __restrict__ pm2,
               const uint16* __restrict__ pg,
               uint32* __restrict__ final_g, uint32* __restrict__ rlist,
               uint32* __restrict__ count, uint64* __restrict__ rkey) {
    const int n = blockIdx.x * THREADS + threadIdx.x;
    float M1 = INFINITY, M2 = INFINITY;
    uint32 G = 0u;
#pragma unroll
    for (int s = 0; s < CS1; ++s) {
        float  m1  = pm1[(size_t)s * NQ + n];
        float  m2s = pm2[(size_t)s * NQ + n];
        uint32 g   = (uint32)pg[(size_t)s * NQ + n];
        float nm2 = fminf(fminf(M2, m2s), fmaxf(M1, m1));
        if (m1 < M1) { M1 = m1; G = g; }    // ascending split -> first-min
        M2 = nm2;
    }
    rkey[n] = ~0ull;                        // init for rescue atomicMin
    if (M2 - M1 > EPS) {
        final_g[n] = G;                     // provably contains the true argmin
    } else {
        final_g[n] = 0xFFFFFFFFu;           // sentinel -> rescue
        uint32 p = atomicAdd(count, 1u);
        rlist[p] = (uint32)n;
    }
}

// RESCUE: exact-grade fp16x2 (6-MFMA, 16x16) full-codebook argmin for flagged
// queries; (score, 4-code-gid) merged via atomicMin on monotone u64 key.
__global__ __launch_bounds__(THREADS, 2)
void vq_rescue(const _Float16* __restrict__ zh1, const _Float16* __restrict__ zh2,
               const _Float16* __restrict__ eh1, const _Float16* __restrict__ eh2,
               const float* __restrict__ norms,
               const uint32* __restrict__ rlist, const uint32* __restrict__ countp,
               uint64* __restrict__ rkey) {
    __shared__ float  redv[4][128];
    __shared__ uint32 redg[4][128];

    const uint32 count = *countp;
    const uint32 nch   = (count + 127u) >> 7;
    const int t    = threadIdx.x;
    const int lane = t & 63;
    const int wave = t >> 6;
    const int r15  = lane & 15, hk = lane >> 4;
    const int cy   = blockIdx.x & 15;
    const int rcb  = cy * 1024 + wave * 256;   // this wave's code range (16 tiles)

    for (uint32 cx = (uint32)(blockIdx.x >> 4); cx < nch; cx += 32u) {
        half8 B1[8][2], B2[8][2];
#pragma unroll
        for (int qt = 0; qt < 8; ++qt) {
            uint32 j = cx * 128u + (uint32)(qt * 16 + r15);
            uint32 qid = (j < count) ? rlist[j] : 0u;
#pragma unroll
            for (int kc = 0; kc < 2; ++kc) {
                size_t off = (size_t)qid * DIM + kc * 32 + hk * 8;
                B1[qt][kc] = *reinterpret_cast<const half8*>(zh1 + off);
                B2[qt][kc] = *reinterpret_cast<const half8*>(zh2 + off);
            }
        }

        float  mv[8];
        uint32 mi[8];
#pragma unroll
        for (int q = 0; q < 8; ++q) { mv[q] = INFINITY; mi[q] = 0u; }

        half8 a1[2], a2[2];
        f32x4 nc;
        {
            const _Float16* p1 = eh1 + (size_t)(rcb + r15) * DIM + hk * 8;
            const _Float16* p2 = eh2 + (size_t)(rcb + r15) * DIM + hk * 8;
            a1[0] = *reinterpret_cast<const half8*>(p1);
            a1[1] = *reinterpret_cast<const half8*>(p1 + 32);
            a2[0] = *reinterpret_cast<const half8*>(p2);
            a2[1] = *reinterpret_cast<const half8*>(p2 + 32);
            nc = *reinterpret_cast<const f32x4*>(norms + rcb + hk * 4);
        }

#pragma unroll 2
        for (int tile = 0; tile < 16; ++tile) {
            int nt = (tile + 1 < 16) ? tile + 1 : tile;
            half8 b1[2], b2[2];
            f32x4 nn;
            {
                const _Float16* p1 = eh1 + (size_t)(rcb + nt * 16 + r15) * DIM + hk * 8;
                const _Float16* p2 = eh2 + (size_t)(rcb + nt * 16 + r15) * DIM + hk * 8;
                b1[0] = *reinterpret_cast<const half8*>(p1);
                b1[1] = *reinterpret_cast<const half8*>(p1 + 32);
                b2[0] = *reinterpret_cast<const half8*>(p2);
                b2[1] = *reinterpret_cast<const half8*>(p2 + 32);
                nn = *reinterpret_cast<const f32x4*>(norms + rcb + nt * 16 + hk * 4);
            }

            f32x4 acc[8];
            __builtin_amdgcn_s_setprio(1);
#pragma unroll
            for (int qt = 0; qt < 8; ++qt) {
                acc[qt] = __builtin_amdgcn_mfma_f32_16x16x32_f16(a1[0], B1[qt][0], nc,      0, 0, 0);
                acc[qt] = __builtin_amdgcn_mfma_f32_16x16x32_f16(a1[1], B1[qt][1], acc[qt], 0, 0, 0);
                acc[qt] = __builtin_amdgcn_mfma_f32_16x16x32_f16(a1[0], B2[qt][0], acc[qt], 0, 0, 0);
                acc[qt] = __builtin_amdgcn_mfma_f32_16x16x32_f16(a1[1], B2[qt][1], acc[qt], 0, 0, 0);
                acc[qt] = __builtin_amdgcn_mfma_f32_16x16x32_f16(a2[0], B1[qt][0], acc[qt], 0, 0, 0);
                acc[qt] = __builtin_amdgcn_mfma_f32_16x16x32_f16(a2[1], B1[qt][1], acc[qt], 0, 0, 0);
            }
            __builtin_amdgcn_s_setprio(0);

            const uint32 tid = (uint32)tile;
#pragma unroll
            for (int qt = 0; qt < 8; ++qt) {
                float v = fminf(fminf(fminf(acc[qt][0], acc[qt][1]), acc[qt][2]), acc[qt][3]);
                bool lt = v < mv[qt];
                mv[qt] = lt ? v : mv[qt];
                mi[qt] = lt ? tid : mi[qt];
            }
            a1[0] = b1[0]; a1[1] = b1[1];
            a2[0] = b2[0]; a2[1] = b2[1];
            nc = nn;
        }

        uint32 gi[8];
#pragma unroll
        for (int q = 0; q < 8; ++q)
            gi[q] = (uint32)(rcb >> 2) + (mi[q] << 2) + (uint32)hk;
#pragma unroll
        for (int st = 16; st < 64; st <<= 1) {
#pragma unroll
            for (int q = 0; q < 8; ++q) {
                float  ov = __shfl_xor(mv[q], st, 64);
                uint32 og = (uint32)__shfl_xor((int)gi[q], st, 64);
                if (ov < mv[q] || (ov == mv[q] && og < gi[q])) { mv[q] = ov; gi[q] = og; }
            }
        }
        if (lane < 16) {
#pragma unroll
            for (int qt = 0; qt < 8; ++qt) {
                redv[wave][qt * 16 + lane] = mv[qt];
                redg[wave][qt * 16 + lane] = gi[qt];
            }
        }
        __syncthreads();
        if (t < 128) {
            float  bv = redv[0][t];
            uint32 bg = redg[0][t];
#pragma unroll
            for (int w = 1; w < 4; ++w) {   // ascending wave = ascending codes
                float v = redv[w][t];
                if (v < bv) { bv = v; bg = redg[w][t]; }
            }
            uint32 j = cx * 128u + (uint32)t;
            if (j < count) {
                uint64 key = ((uint64)fmono(bv) << 32) | (uint64)bg;
                atomicMin(rkey + rlist[j], key);
            }
        }
        __syncthreads();   // LDS reuse across cx iterations
    }
}

// FINALIZE: unified 16-candidate path. Margin queries: group = pass1 16-gid.
// Rescued queries: the 4-code quad lies inside one (tile,hi) 16-group ->
// superset decode. 4 lanes/query; exact fp32 re-eval, ascending code = first-min.
__global__ __launch_bounds__(THREADS)
void vq_finalize(const float* __restrict__ z,
                 const float* __restrict__ emb,
                 const float* __restrict__ norms,
                 const uint32* __restrict__ final_g,
                 const uint64* __restrict__ rkey,
                 float* __restrict__ out,
                 float* __restrict__ lossp) {
    const int t  = threadIdx.x;
    const int ql = t >> 2, p = t & 3;
    const int n  = blockIdx.x * 64 + ql;
    const int c0 = p * 16;

    uint32 bg = final_g[n];
    if (bg == 0xFFFFFFFFu) {
        uint32 c4 = (uint32)(rkey[n] & 0xFFFFFFFFull) * 4u;   // first code of quad
        bg = (c4 >> 5) * 2u + ((c4 >> 2) & 1u);
    }
    const int gbase = (int)((bg >> 1) * 32u + (bg & 1u) * 4u);

    const float* zp = z + (size_t)(n >> 10) * 65536 + (n & 1023);
    float zq[16];
#pragma unroll
    for (int c = 0; c < 16; ++c) zq[c] = zp[(size_t)(c0 + c) * 1024];

    // partial dots over this lane's 16 channels, 16 candidates
    float dp[16];
#pragma unroll
    for (int j = 0; j < 16; ++j) {
        int code = gbase + (j & 3) + 8 * (j >> 2);
        const float4* er = reinterpret_cast<const float4*>(emb + (size_t)code * DIM + c0);
        float d = 0.f;
#pragma unroll
        for (int i = 0; i < 4; ++i) {
            float4 e4 = er[i];
            d = fmaf(e4.x, zq[i * 4 + 0], d);
            d = fmaf(e4.y, zq[i * 4 + 1], d);
            d = fmaf(e4.z, zq[i * 4 + 2], d);
            d = fmaf(e4.w, zq[i * 4 + 3], d);
        }
        dp[j] = d;
    }
#pragma unroll
    for (int st = 1; st < 4; st <<= 1) {
#pragma unroll
        for (int j = 0; j < 16; ++j) dp[j] += __shfl_xor(dp[j], st, 64);
    }

    f32x4 nr[4];
#pragma unroll
    for (int k = 0; k < 4; ++k)
        nr[k] = *reinterpret_cast<const f32x4*>(norms + gbase + k * 8);

    float bs = INFINITY;
    uint32 bi = 0u;
#pragma unroll
    for (int j = 0; j < 16; ++j) {   // ascending code order within group
        float s = fmaf(-2.f, dp[j], nr[j >> 2][j & 3]);
        uint32 code = (uint32)(gbase + (j & 3) + 8 * (j >> 2));
        if (s < bs) { bs = s; bi = code; }   // strict < -> first-min
    }

    const float* ew = emb + (size_t)bi * DIM + c0;
    float* op = out + (size_t)(n >> 10) * 65536 + (n & 1023);

    float ls = 0.f;
#pragma unroll
    for (int c = 0; c < 16; ++c) {
        float e = ew[c];
        op[(size_t)(c0 + c) * 1024] = e;
        float d = e - zq[c];
        ls = fmaf(d, d, ls);
    }

#pragma unroll
    for (int off = 32; off > 0; off >>= 1) ls += __shfl_down(ls, off, 64);
    __shared__ float wsum[THREADS / 64];
    if ((t & 63) == 0) wsum[t >> 6] = ls;
    __syncthreads();
    if (t == 0) {
        float s = 0.f;
#pragma unroll
        for (int w = 0; w < THREADS / 64; ++w) s += wsum[w];
        lossp[blockIdx.x] = s;
    }
}

__global__ __launch_bounds__(64)
void vq_loss_final(const float* __restrict__ lossp, float* __restrict__ out) {
    float v = 0.f;
#pragma unroll
    for (int k = 0; k < 4; ++k) v += lossp[threadIdx.x + k * 64];
#pragma unroll
    for (int off = 32; off > 0; off >>= 1) v += __shfl_down(v, off, 64);
    if (threadIdx.x == 0)
        out[1048576] = 0.25f * v / 1048576.0f;   // BETA * mean
}

extern "C" void kernel_launch(void* const* d_in, const int* in_sizes, int n_in,
                              void* d_out, int out_size, void* d_ws, size_t ws_size,
                              hipStream_t stream) {
    const float* z   = (const float*)d_in[0];
    const float* emb = (const float*)d_in[1];
    float* out = (float*)d_out;

    float* ws = (float*)d_ws;
    float*     norms   = ws + W_NORMS;
    float*     pm1     = ws + W_PM1;
    float*     pm2     = ws + W_PM2;
    uint16*    pg      = (uint16*)(ws + W_PG);
    uint32*    final_g = (uint32*)(ws + W_FINALG);
    uint32*    rlist   = (uint32*)(ws + W_RLIST);
    uint32*    count   = (uint32*)(ws + W_COUNT);
    float*     lossp   = ws + W_LOSSP;
    uint64*    rkey    = (uint64*)(ws + W_RKEY);
    _Float16*  zh1     = (_Float16*)(ws + W_ZH1);
    _Float16*  zh2     = (_Float16*)(ws + W_ZH2);
    _Float16*  eh1     = (_Float16*)(ws + W_EH1);
    _Float16*  eh2     = (_Float16*)(ws + W_EH2);

    vq_prep<<<512, THREADS, 0, stream>>>(z, emb, zh1, zh2, eh1, eh2, norms, count);

    dim3 g1(NQ / QB, CS1);   // 64 x 8 = 512 blocks
    vq_pass1<<<g1, THREADS, 0, stream>>>(zh1, eh1, norms, pm1, pm2, pg);

    vq_select<<<NQ / THREADS, THREADS, 0, stream>>>(pm1, pm2, pg, final_g, rlist, count, rkey);

    vq_rescue<<<512, THREADS, 0, stream>>>(zh1, zh2, eh1, eh2, norms, rlist, count, rkey);

    vq_finalize<<<NQ / 64, THREADS, 0, stream>>>(z, emb, norms, final_g, rkey, out, lossp);
    vq_loss_final<<<1, 64, 0, stream>>>(lossp, out);
}